// Round 9
// baseline (861.043 us; speedup 1.0000x reference)
//
#include <hip/hip_runtime.h>

// PairwiseMLPLinkPredictor on MI355X (gfx950)
// feats = bf16(x[u]) * bf16(x[v]);  h1 = relu(feats@W1+b1);  h2 = relu(h1@W2+b2);
// out = h2@W3 + b3.
//
// R8 = R4b (388 us best) + targeted LDS-pipe cut, keeping R4b's cache regime:
//  - NT hints on ep + gather loads (protects 192 KB weight set in L2 from the
//    ~1 GB gather sweep; R4b FETCH 0.48 GB vs 1.5-2.3 GB without).
//  - forced 1 block/CU via __launch_bounds__(1024,4): 2 blocks/CU doubles
//    gather concurrency -> FETCH blowup (R5/R6 evidence).
//  - GEMM1 wave grid M2xN8 (wave = 32 rows x 32 cols): halves the dominant
//    LDS term (A-fragment reads 6.1K -> 3K cyc/tile).
//  - separate 32 KB h1 buffer: 2 barriers/tile, single 32 KB feats buffer.
//  - layer 3 via LDS ss[] + single store (R4b's global atomics = 125 MB WRITE).

typedef __attribute__((ext_vector_type(8))) short short8;   // 8 bf16 = 4 VGPRs
typedef __attribute__((ext_vector_type(4))) float floatx4;  // MFMA C/D frag
typedef __attribute__((ext_vector_type(4))) unsigned uintx4;
typedef __attribute__((ext_vector_type(2))) int intx2;

#define MT 64         // pairs per tile
#define NTHREADS 1024 // 16 waves
#define NBLOCKS 512   // persistent-ish; 1 block/CU resident

__device__ __forceinline__ unsigned short f2bf(float f) {
  union { float f; unsigned u; } a; a.f = f;
  unsigned r = a.u + 0x7FFFu + ((a.u >> 16) & 1u);   // RNE
  return (unsigned short)(r >> 16);
}

// packed bf16 x2 multiply via f32 (unpack, mul, RNE repack)
__device__ __forceinline__ unsigned bf16mul2(unsigned ua, unsigned ub) {
  float lo = __uint_as_float(ua << 16)          * __uint_as_float(ub << 16);
  float hi = __uint_as_float(ua & 0xFFFF0000u) * __uint_as_float(ub & 0xFFFF0000u);
  return (unsigned)f2bf(lo) | ((unsigned)f2bf(hi) << 16);
}

// ---------- prologue: x -> bf16 table ----------
__global__ void cast_x_kernel(const float* __restrict__ x, unsigned short* __restrict__ xb, int n4) {
  int i = blockIdx.x * blockDim.x + threadIdx.x;
  if (i >= n4) return;
  float4 v = ((const float4*)x)[i];
  ushort4 o;
  o.x = f2bf(v.x); o.y = f2bf(v.y); o.z = f2bf(v.z); o.w = f2bf(v.w);
  ((ushort4*)xb)[i] = o;
}

// ---------- prologue: W1 [256,256] / W2 [256,128] -> bf16, transposed to [n][k] ----------
__global__ void prep_w_kernel(const float* __restrict__ W1, const float* __restrict__ W2,
                              unsigned short* __restrict__ w1t, unsigned short* __restrict__ w2t) {
  int i = blockIdx.x * blockDim.x + threadIdx.x;
  if (i < 256 * 256) {
    int k = i >> 8, n = i & 255;
    w1t[n * 256 + k] = f2bf(W1[k * 256 + n]);
  } else {
    int j = i - 256 * 256;
    if (j < 128 * 256) {
      int k = j >> 7, n = j & 127;
      w2t[n * 256 + k] = f2bf(W2[k * 128 + n]);
    }
  }
}

// ---------- fused pairwise MLP, persistent + pipelined ----------
__global__ __launch_bounds__(NTHREADS, 4) void mlp_kernel(
    const unsigned short* __restrict__ xb,
    const unsigned short* __restrict__ w1t,
    const unsigned short* __restrict__ w2t,
    const float* __restrict__ b1,
    const float* __restrict__ b2,
    const float* __restrict__ w3,
    const float* __restrict__ b3,
    const int* __restrict__ ep,
    float* __restrict__ out,
    int E)
{
  // Row stride 512 B; 16B chunks XOR-swizzled by (row & 15): conflict-free
  // stride-512 ds_read_b128 without padding. fbuf: feats (single buffer —
  // staging happens after B1 when feats are dead); h1buf disjoint.
  __shared__ __align__(16) unsigned short fbuf[MT * 256];   // 32 KB
  __shared__ __align__(16) unsigned short h1buf[MT * 256];  // 32 KB
  __shared__ float ss[MT];

  const int tid  = threadIdx.x;
  const int wv   = tid >> 6;      // 0..15
  const int lane = tid & 63;
  const int q    = lane >> 4;     // quad 0..3
  const int r16  = lane & 15;
  const int c    = tid & 31;      // 16B chunk within 512B row (staging)
  const int mr0  = tid >> 5;      // staging rows mr0, mr0+32
  const int mg   = wv >> 3;       // 0..1: 32-row slab (both GEMMs)
  const int ng   = wv & 7;        // 0..7: 32-col slab (GEMM1) / 16-col (GEMM2)
  const int swz16 = (q ^ r16) << 4;
  char* const fb  = (char*)fbuf;
  char* const h1b = (char*)h1buf;

  const int ntiles = (E + MT - 1) / MT;
  const float b3v = b3[0];

  if (tid < MT) ss[tid] = 0.f;

  // ---- prologue: stage tile t0 into fbuf ----
  {
    int t0 = blockIdx.x;
    #pragma unroll
    for (int s = 0; s < 2; ++s) {
      int m = mr0 + 32 * s;
      int g = t0 * MT + m; if (g >= E) g = E - 1;
      intx2 uv = __builtin_nontemporal_load((const intx2*)(ep + 2 * (size_t)g));
      uintx4 a = __builtin_nontemporal_load((const uintx4*)(xb + ((size_t)uv.x << 8) + (c << 3)));
      uintx4 b = __builtin_nontemporal_load((const uintx4*)(xb + ((size_t)uv.y << 8) + (c << 3)));
      uintx4 pv;
      #pragma unroll
      for (int tt = 0; tt < 4; ++tt) pv[tt] = bf16mul2(a[tt], b[tt]);
      *(uintx4*)(fb + m * 512 + ((c ^ (m & 15)) << 4)) = pv;
    }
  }
  __syncthreads();

  for (int t = blockIdx.x; t < ntiles; t += NBLOCKS) {
    const int tn = (t + NBLOCKS < ntiles) ? (t + NBLOCKS) : t;

    // ---- (1) prefetch ep indices for next tile ----
    intx2 uvn[2];
    #pragma unroll
    for (int s = 0; s < 2; ++s) {
      int g = tn * MT + mr0 + 32 * s; if (g >= E) g = E - 1;
      uvn[s] = __builtin_nontemporal_load((const intx2*)(ep + 2 * (size_t)g));
    }

    // ---- (2) GEMM1: wave owns 32 rows x 32 cols; B preloaded per K-half ----
    const unsigned short* const b1p0 = w1t + (ng * 32 + r16) * 256 + q * 8;   // nt=0
    const unsigned short* const b1p1 = b1p0 + 16 * 256;                        // nt=1
    floatx4 acc[2][2];
    #pragma unroll
    for (int i = 0; i < 2; ++i)
      #pragma unroll
      for (int j = 0; j < 2; ++j)
        acc[i][j] = (floatx4){0.f, 0.f, 0.f, 0.f};

    char* const a1base = fb + (mg * 32 + r16) * 512;
    #pragma unroll
    for (int half = 0; half < 2; ++half) {
      short8 bv[2][4];
      #pragma unroll
      for (int kk = 0; kk < 4; ++kk) {
        bv[0][kk] = *(const short8*)(b1p0 + (half * 4 + kk) * 32);
        bv[1][kk] = *(const short8*)(b1p1 + (half * 4 + kk) * 32);
      }
      #pragma unroll
      for (int kk = 0; kk < 4; ++kk) {
        const int kt = half * 4 + kk;
        const int aoff = (kt << 6) ^ swz16;
        short8 av0 = *(const short8*)(a1base + aoff);
        short8 av1 = *(const short8*)(a1base + 16 * 512 + aoff);
        acc[0][0] = __builtin_amdgcn_mfma_f32_16x16x32_bf16(av0, bv[0][kk], acc[0][0], 0, 0, 0);
        acc[0][1] = __builtin_amdgcn_mfma_f32_16x16x32_bf16(av0, bv[1][kk], acc[0][1], 0, 0, 0);
        acc[1][0] = __builtin_amdgcn_mfma_f32_16x16x32_bf16(av1, bv[0][kk], acc[1][0], 0, 0, 0);
        acc[1][1] = __builtin_amdgcn_mfma_f32_16x16x32_bf16(av1, bv[1][kk], acc[1][1], 0, 0, 0);
      }
    }

    // ---- (3) h1 writeback (bias+relu, bf16) -> h1buf (disjoint buffer) ----
    {
      #pragma unroll
      for (int nt = 0; nt < 2; ++nt) {
        const int n1 = ng * 32 + nt * 16 + r16;
        const float bias1 = b1[n1];
        #pragma unroll
        for (int mt = 0; mt < 2; ++mt) {
          #pragma unroll
          for (int r = 0; r < 4; ++r) {
            int mlo = q * 4 + r;                  // C/D: row = 4*quad + reg
            int m = mg * 32 + mt * 16 + mlo;
            float h = fmaxf(acc[mt][nt][r] + bias1, 0.f);
            int ch = (n1 >> 3) ^ mlo;
            *(unsigned short*)(h1b + m * 512 + (ch << 4) + ((n1 & 7) << 1)) = f2bf(h);
          }
        }
      }
    }
    __syncthreads();   // B1: h1 ready; feats in fbuf dead

    // ---- (4) GEMM2 B preload, then issue next-tile gather loads (NT) ----
    const unsigned short* const b2p = w2t + (ng * 16 + r16) * 256 + q * 8;
    short8 bv2[8];
    #pragma unroll
    for (int kt = 0; kt < 8; ++kt) bv2[kt] = *(const short8*)(b2p + kt * 32);

    uintx4 ra[2], rb[2];
    #pragma unroll
    for (int s = 0; s < 2; ++s) {
      ra[s] = __builtin_nontemporal_load((const uintx4*)(xb + ((size_t)uvn[s].x << 8) + (c << 3)));
      rb[s] = __builtin_nontemporal_load((const uintx4*)(xb + ((size_t)uvn[s].y << 8) + (c << 3)));
    }

    // ---- (5) GEMM2: wave owns 32 rows x 16 cols; K=256 ----
    floatx4 acc2[2];
    acc2[0] = (floatx4){0.f, 0.f, 0.f, 0.f};
    acc2[1] = (floatx4){0.f, 0.f, 0.f, 0.f};
    char* const a2base = h1b + (mg * 32 + r16) * 512;
    #pragma unroll
    for (int kt = 0; kt < 8; ++kt) {
      const int aoff = (kt << 6) ^ swz16;
      short8 av0 = *(const short8*)(a2base + aoff);
      short8 av1 = *(const short8*)(a2base + 16 * 512 + aoff);
      acc2[0] = __builtin_amdgcn_mfma_f32_16x16x32_bf16(av0, bv2[kt], acc2[0], 0, 0, 0);
      acc2[1] = __builtin_amdgcn_mfma_f32_16x16x32_bf16(av1, bv2[kt], acc2[1], 0, 0, 0);
    }

    // ---- (6) fused layer 3 partials -> LDS ss[] ----
    {
      const int n2 = ng * 16 + r16;
      const float b2v = b2[n2];
      const float w3v = w3[n2];
      #pragma unroll
      for (int mt = 0; mt < 2; ++mt) {
        #pragma unroll
        for (int r = 0; r < 4; ++r) {
          float h = fmaxf(acc2[mt][r] + b2v, 0.f);
          float pp = h * w3v;
          pp += __shfl_xor(pp, 1);
          pp += __shfl_xor(pp, 2);
          pp += __shfl_xor(pp, 4);
          pp += __shfl_xor(pp, 8);
          if (r16 == 0)
            atomicAdd(&ss[mg * 32 + mt * 16 + q * 4 + r], pp);
        }
      }
    }

    // ---- (7) stage next tile's feats into fbuf (dead since B1) ----
    #pragma unroll
    for (int s = 0; s < 2; ++s) {
      int m = mr0 + 32 * s;
      uintx4 pv;
      #pragma unroll
      for (int tt = 0; tt < 4; ++tt) pv[tt] = bf16mul2(ra[s][tt], rb[s][tt]);
      *(uintx4*)(fb + m * 512 + ((c ^ (m & 15)) << 4)) = pv;
    }
    __syncthreads();   // B2: ss complete, next feats staged, h1 reads done

    // ---- (8) store scores; re-init ss (ordered vs next atomics by B1) ----
    if (tid < MT) {
      int g = t * MT + tid;
      if (g < E) out[g] = ss[tid] + b3v;
      ss[tid] = 0.f;
    }
  }
}

extern "C" void kernel_launch(void* const* d_in, const int* in_sizes, int n_in,
                              void* d_out, int out_size, void* d_ws, size_t ws_size,
                              hipStream_t stream) {
  const float* x  = (const float*)d_in[0];
  const float* W1 = (const float*)d_in[1];
  const float* b1 = (const float*)d_in[2];
  const float* W2 = (const float*)d_in[3];
  const float* b2 = (const float*)d_in[4];
  const float* W3 = (const float*)d_in[5];
  const float* b3 = (const float*)d_in[6];
  // d_in[7] = edge_index (unused by the reference computation)
  const int*   ep = (const int*)d_in[8];
  float* out = (float*)d_out;

  const int NX = in_sizes[0];        // 100000*256 = 25,600,000
  const int E  = in_sizes[8] / 2;    // 1,000,000

  // workspace layout: xb (NX bf16) | w1t (256*256 bf16) | w2t (128*256 bf16)  ~49 MB
  unsigned short* xb  = (unsigned short*)d_ws;
  unsigned short* w1t = (unsigned short*)((char*)d_ws + (size_t)NX * 2);
  unsigned short* w2t = w1t + 256 * 256;

  cast_x_kernel<<<(NX / 4 + 255) / 256, 256, 0, stream>>>(x, xb, NX / 4);
  prep_w_kernel<<<(256 * 256 + 128 * 256 + 255) / 256, 256, 0, stream>>>(W1, W2, w1t, w2t);
  mlp_kernel<<<NBLOCKS, NTHREADS, 0, stream>>>(xb, w1t, w2t, b1, b2, W3, b3, ep, out, E);
}

// Round 10
// 543.505 us; speedup vs baseline: 1.5842x; 1.5842x over previous
//
#include <hip/hip_runtime.h>

// PairwiseMLPLinkPredictor on MI355X (gfx950)
// feats = bf16(x[u]) * bf16(x[v]);  h1 = relu(feats@W1+b1);  h2 = relu(h1@W2+b2);
// out = h2@W3 + b3.
//
// R9 = R4b (388 us empirical best) with ONE change: MT 64 -> 128.
// Sacred (empirical law, 9 rounds): GEMM1 N16 no-dup wave slabs (block covers
// N=256 exactly once), NT gather loads, 1 block/CU, batch weight preloads off
// the K-loop critical path. Any deviation (N32 dup slabs, 2 blocks/CU, per-kt
// weight loads) -> FETCH 0.48 -> 1.3-2.3 GB and ~2x slowdown (R5-R8).
// MT=128 halves per-pair barrier count and weight-load drains. Layer 3 via
// LDS ss[] + coalesced store (drops R4b's 242 MB global-atomic write-through).

typedef __attribute__((ext_vector_type(8))) short short8;   // 8 bf16 = 4 VGPRs
typedef __attribute__((ext_vector_type(4))) float floatx4;  // MFMA C/D frag
typedef __attribute__((ext_vector_type(4))) unsigned uintx4;
typedef __attribute__((ext_vector_type(2))) int intx2;

#define MT 128        // pairs per tile
#define NTHREADS 1024 // 16 waves
#define NBLOCKS 256   // persistent, 1 block/CU (128.5 KB LDS forces it)

__device__ __forceinline__ unsigned short f2bf(float f) {
  union { float f; unsigned u; } a; a.f = f;
  unsigned r = a.u + 0x7FFFu + ((a.u >> 16) & 1u);   // RNE
  return (unsigned short)(r >> 16);
}

// packed bf16 x2 multiply via f32 (unpack, mul, RNE repack)
__device__ __forceinline__ unsigned bf16mul2(unsigned ua, unsigned ub) {
  float lo = __uint_as_float(ua << 16)          * __uint_as_float(ub << 16);
  float hi = __uint_as_float(ua & 0xFFFF0000u) * __uint_as_float(ub & 0xFFFF0000u);
  return (unsigned)f2bf(lo) | ((unsigned)f2bf(hi) << 16);
}

// ---------- prologue: x -> bf16 table ----------
__global__ void cast_x_kernel(const float* __restrict__ x, unsigned short* __restrict__ xb, int n4) {
  int i = blockIdx.x * blockDim.x + threadIdx.x;
  if (i >= n4) return;
  float4 v = ((const float4*)x)[i];
  ushort4 o;
  o.x = f2bf(v.x); o.y = f2bf(v.y); o.z = f2bf(v.z); o.w = f2bf(v.w);
  ((ushort4*)xb)[i] = o;
}

// ---------- prologue: W1 [256,256] / W2 [256,128] -> bf16, transposed to [n][k] ----------
__global__ void prep_w_kernel(const float* __restrict__ W1, const float* __restrict__ W2,
                              unsigned short* __restrict__ w1t, unsigned short* __restrict__ w2t) {
  int i = blockIdx.x * blockDim.x + threadIdx.x;
  if (i < 256 * 256) {
    int k = i >> 8, n = i & 255;
    w1t[n * 256 + k] = f2bf(W1[k * 256 + n]);
  } else {
    int j = i - 256 * 256;
    if (j < 128 * 256) {
      int k = j >> 7, n = j & 127;
      w2t[n * 256 + k] = f2bf(W2[k * 128 + n]);
    }
  }
}

// ---------- fused pairwise MLP, persistent + pipelined, double buffer ----------
__global__ __launch_bounds__(NTHREADS, 4) void mlp_kernel(
    const unsigned short* __restrict__ xb,
    const unsigned short* __restrict__ w1t,
    const unsigned short* __restrict__ w2t,
    const float* __restrict__ b1,
    const float* __restrict__ b2,
    const float* __restrict__ w3,
    const float* __restrict__ b3,
    const int* __restrict__ ep,
    float* __restrict__ out,
    int E)
{
  // 2 x (128 rows x 256 bf16) = 2 x 64 KB. Row stride 512 B; 16B chunks
  // XOR-swizzled by (row & 15): conflict-free stride-512 ds_read_b128.
  // h1 written in place over feats (R4b pattern); staging goes to the other buffer.
  __shared__ __align__(16) unsigned short buf[2][MT * 256];
  __shared__ float ss[MT];

  const int tid  = threadIdx.x;
  const int wv   = tid >> 6;      // 0..15
  const int lane = tid & 63;
  const int q    = lane >> 4;     // quad 0..3
  const int r16  = lane & 15;
  const int c    = tid & 31;      // 16B chunk within 512B row (staging)
  const int mr0  = tid >> 5;      // staging rows mr0 + 32*s, s=0..3
  const int swz16 = (q ^ r16) << 4;

  const int ntiles = (E + MT - 1) / MT;
  const float b3v = b3[0];

  if (tid < MT) ss[tid] = 0.f;

  // ---- prologue: stage tile t0 into buf[0] ----
  {
    int t0 = blockIdx.x;
    #pragma unroll
    for (int s = 0; s < 4; ++s) {
      int m = mr0 + 32 * s;
      int g = t0 * MT + m; if (g >= E) g = E - 1;
      intx2 uv = __builtin_nontemporal_load((const intx2*)(ep + 2 * (size_t)g));
      uintx4 a = __builtin_nontemporal_load((const uintx4*)(xb + ((size_t)uv.x << 8) + (c << 3)));
      uintx4 b = __builtin_nontemporal_load((const uintx4*)(xb + ((size_t)uv.y << 8) + (c << 3)));
      uintx4 pv;
      #pragma unroll
      for (int tt = 0; tt < 4; ++tt) pv[tt] = bf16mul2(a[tt], b[tt]);
      *(uintx4*)((char*)buf[0] + m * 512 + ((c ^ (m & 15)) << 4)) = pv;
    }
  }
  __syncthreads();

  int p = 0;
  for (int t = blockIdx.x; t < ntiles; t += NBLOCKS) {
    char* const bufp = (char*)buf[p];
    char* const bufn = (char*)buf[p ^ 1];
    const int tn = (t + NBLOCKS < ntiles) ? (t + NBLOCKS) : t;

    // ---- (1) prefetch ep indices for next tile ----
    intx2 uvn[4];
    #pragma unroll
    for (int s = 0; s < 4; ++s) {
      int g = tn * MT + mr0 + 32 * s; if (g >= E) g = E - 1;
      uvn[s] = __builtin_nontemporal_load((const intx2*)(ep + 2 * (size_t)g));
    }

    // ---- (2) GEMM1: wave owns 128 rows x 16 cols (n = wv*16+r16, NO dup) ----
    const unsigned short* const b1p = w1t + (wv * 16 + r16) * 256 + q * 8;
    short8 bv1[8];
    #pragma unroll
    for (int kt = 0; kt < 8; ++kt) bv1[kt] = *(const short8*)(b1p + kt * 32);

    floatx4 acc[8];
    #pragma unroll
    for (int i = 0; i < 8; ++i) acc[i] = (floatx4){0.f, 0.f, 0.f, 0.f};

    char* const a1base = bufp + r16 * 512;
    #pragma unroll
    for (int kt = 0; kt < 8; ++kt) {
      const int aoff = (kt << 6) ^ swz16;
      short8 av[8];
      #pragma unroll
      for (int mt = 0; mt < 8; ++mt)
        av[mt] = *(const short8*)(a1base + mt * (16 * 512) + aoff);
      #pragma unroll
      for (int mt = 0; mt < 8; ++mt)
        acc[mt] = __builtin_amdgcn_mfma_f32_16x16x32_bf16(av[mt], bv1[kt], acc[mt], 0, 0, 0);
    }
    __syncthreads();   // B1: all feat reads from bufp done

    // ---- (3) h1 writeback (bias+relu, bf16) in place into bufp, swizzled ----
    {
      const int n1 = wv * 16 + r16;
      const float bias1 = b1[n1];
      #pragma unroll
      for (int mt = 0; mt < 8; ++mt) {
        #pragma unroll
        for (int r = 0; r < 4; ++r) {
          int m = mt * 16 + q * 4 + r;            // C/D: row = 4*quad + reg
          float h = fmaxf(acc[mt][r] + bias1, 0.f);
          int ch = (n1 >> 3) ^ (m & 15);
          *(unsigned short*)(bufp + m * 512 + (ch << 4) + ((n1 & 7) << 1)) = f2bf(h);
        }
      }
    }
    __syncthreads();   // B2: h1 ready

    // ---- (4) GEMM2 B preload, then issue next-tile gather loads (NT) ----
    const int mg2 = wv >> 3;        // 0..1: 64-row slab (4 m-tiles)
    const int ng2 = wv & 7;         // 0..7: 16-col slab
    const unsigned short* const b2p = w2t + (ng2 * 16 + r16) * 256 + q * 8;
    short8 bv2[8];
    #pragma unroll
    for (int kt = 0; kt < 8; ++kt) bv2[kt] = *(const short8*)(b2p + kt * 32);

    uintx4 ra[4], rb[4];
    #pragma unroll
    for (int s = 0; s < 4; ++s) {
      ra[s] = __builtin_nontemporal_load((const uintx4*)(xb + ((size_t)uvn[s].x << 8) + (c << 3)));
      rb[s] = __builtin_nontemporal_load((const uintx4*)(xb + ((size_t)uvn[s].y << 8) + (c << 3)));
    }

    // ---- (5) GEMM2: wave owns 64 rows x 16 cols; K=256 ----
    floatx4 acc2[4];
    #pragma unroll
    for (int i = 0; i < 4; ++i) acc2[i] = (floatx4){0.f, 0.f, 0.f, 0.f};
    char* const a2base = bufp + (mg2 * 64 + r16) * 512;
    #pragma unroll
    for (int kt = 0; kt < 8; ++kt) {
      const int aoff = (kt << 6) ^ swz16;
      short8 av[4];
      #pragma unroll
      for (int mt = 0; mt < 4; ++mt)
        av[mt] = *(const short8*)(a2base + mt * (16 * 512) + aoff);
      #pragma unroll
      for (int mt = 0; mt < 4; ++mt)
        acc2[mt] = __builtin_amdgcn_mfma_f32_16x16x32_bf16(av[mt], bv2[kt], acc2[mt], 0, 0, 0);
    }

    // ---- (6) fused layer 3 partials -> LDS ss[] ----
    {
      const int n2 = ng2 * 16 + r16;
      const float b2v = b2[n2];
      const float w3v = w3[n2];
      #pragma unroll
      for (int mt = 0; mt < 4; ++mt) {
        #pragma unroll
        for (int r = 0; r < 4; ++r) {
          float h = fmaxf(acc2[mt][r] + b2v, 0.f);
          float pp = h * w3v;
          pp += __shfl_xor(pp, 1);
          pp += __shfl_xor(pp, 2);
          pp += __shfl_xor(pp, 4);
          pp += __shfl_xor(pp, 8);
          if (r16 == 0)
            atomicAdd(&ss[mg2 * 64 + mt * 16 + q * 4 + r], pp);
        }
      }
    }

    // ---- (7) stage next tile's feats into bufn (disjoint from bufp) ----
    #pragma unroll
    for (int s = 0; s < 4; ++s) {
      int m = mr0 + 32 * s;
      uintx4 pv;
      #pragma unroll
      for (int tt = 0; tt < 4; ++tt) pv[tt] = bf16mul2(ra[s][tt], rb[s][tt]);
      *(uintx4*)(bufn + m * 512 + ((c ^ (m & 15)) << 4)) = pv;
    }
    __syncthreads();   // B3: ss complete, bufn staged, bufp reads done

    // ---- (8) store scores; re-init ss (next atomics are after B1'/B2') ----
    if (tid < MT) {
      int g = t * MT + tid;
      if (g < E) out[g] = ss[tid] + b3v;
      ss[tid] = 0.f;
    }
    p ^= 1;
  }
}

extern "C" void kernel_launch(void* const* d_in, const int* in_sizes, int n_in,
                              void* d_out, int out_size, void* d_ws, size_t ws_size,
                              hipStream_t stream) {
  const float* x  = (const float*)d_in[0];
  const float* W1 = (const float*)d_in[1];
  const float* b1 = (const float*)d_in[2];
  const float* W2 = (const float*)d_in[3];
  const float* b2 = (const float*)d_in[4];
  const float* W3 = (const float*)d_in[5];
  const float* b3 = (const float*)d_in[6];
  // d_in[7] = edge_index (unused by the reference computation)
  const int*   ep = (const int*)d_in[8];
  float* out = (float*)d_out;

  const int NX = in_sizes[0];        // 100000*256 = 25,600,000
  const int E  = in_sizes[8] / 2;    // 1,000,000

  // workspace layout: xb (NX bf16) | w1t (256*256 bf16) | w2t (128*256 bf16)  ~49 MB
  unsigned short* xb  = (unsigned short*)d_ws;
  unsigned short* w1t = (unsigned short*)((char*)d_ws + (size_t)NX * 2);
  unsigned short* w2t = w1t + 256 * 256;

  cast_x_kernel<<<(NX / 4 + 255) / 256, 256, 0, stream>>>(x, xb, NX / 4);
  prep_w_kernel<<<(256 * 256 + 128 * 256 + 255) / 256, 256, 0, stream>>>(W1, W2, w1t, w2t);
  mlp_kernel<<<NBLOCKS, NTHREADS, 0, stream>>>(xb, w1t, w2t, b1, b2, W3, b3, ep, out, E);
}